// Round 1
// 424.186 us; speedup vs baseline: 1.0308x; 1.0308x over previous
//
#include <hip/hip_runtime.h>

// STDPLinear fully-fused single kernel for MI355X (gfx950) — 2 rows per block.
// Outputs (flat, fp32): [0,8192) out_spikes | [8192,16384) new_membrane |
// [16384,24576) new_delta_pre | [24576,32768) new_delta_fire | [32768,...) new_weights (8192x8192)
//
// Roofline: W read (268 MB) + W' write (268 MB) = 537 MB HBM -> ~85 us @ 6.3 TB/s.
// v2 structure: each block owns rows (2b, 2b+1).
//  - 16 outstanding nontemporal streaming loads per thread (2x MLP of v1) hide the
//    reduce/barrier bubble.
//  - in_spikes/delta_pre read ONCE per block (they are row-invariant), and the
//    packed LUT indices are shared by both rows.
//  - The two 51-lane expf LUT builds run concurrently on wave 0 (row0) and
//    wave 1 (row1) between the same barrier pair: 2 barriers per 2 rows.

#define IN_F 8192
#define OUT_F 8192

typedef float v4f __attribute__((ext_vector_type(4)));

__global__ __launch_bounds__(256) void stdp_fused2(
    const float* __restrict__ in_spikes,
    const float* __restrict__ W,
    const float* __restrict__ membrane,
    const float* __restrict__ delta_pre,
    const float* __restrict__ delta_fire,
    float* __restrict__ out)
{
    constexpr float kBeta   = 0.99f;
    constexpr float kThresh = 1.0f;
    constexpr float kReset  = 0.8f;
    constexpr float kInvTau = 1.0f / 20.0f;
    constexpr float kA      = 0.005f;

    const int r0 = blockIdx.x * 2;
    const int r1 = r0 + 1;
    const int t  = threadIdx.x;

    // Wave-uniform scalar loads -> s_load at entry, latency hidden under pass 1.
    const float m0  = membrane[r0];
    const float m1  = membrane[r1];
    const float df0 = delta_fire[r0];
    const float df1 = delta_fire[r1];

    const float* wr0 = W + (size_t)r0 * IN_F;
    const float* wr1 = W + (size_t)r1 * IN_F;

    // ---- pass 1: stream both rows into registers, dual dot product,
    //      packed LUT indices built once (row-invariant) ----
    v4f w0[8], w1[8];
    unsigned int packed[8];   // 4 x 8-bit new_delta_pre indices (0..50) per chunk
    float acc0 = 0.0f, acc1 = 0.0f;
#pragma unroll
    for (int k = 0; k < 8; ++k) {
        const int c = k * 1024 + t * 4;                 // coalesced float4 per chunk
        w0[k] = __builtin_nontemporal_load((const v4f*)(wr0 + c));  // streaming
        w1[k] = __builtin_nontemporal_load((const v4f*)(wr1 + c));  // streaming
        const v4f s  = *(const v4f*)(in_spikes + c);    // hot, L1/L2 resident
        const v4f dp = *(const v4f*)(delta_pre + c);
        acc0 += w0[k].x * s.x + w0[k].y * s.y + w0[k].z * s.z + w0[k].w * s.w;
        acc1 += w1[k].x * s.x + w1[k].y * s.y + w1[k].z * s.z + w1[k].w * s.w;
        const unsigned i0 = (s.x > 0.0f) ? 0u : (unsigned)(dp.x + 1.0f);
        const unsigned i1 = (s.y > 0.0f) ? 0u : (unsigned)(dp.y + 1.0f);
        const unsigned i2 = (s.z > 0.0f) ? 0u : (unsigned)(dp.z + 1.0f);
        const unsigned i3 = (s.w > 0.0f) ? 0u : (unsigned)(dp.w + 1.0f);
        packed[k] = i0 | (i1 << 8) | (i2 << 16) | (i3 << 24);
    }

    // dual wave(64) shuffle reduce, then cross-wave via LDS
#pragma unroll
    for (int off = 32; off > 0; off >>= 1) {
        acc0 += __shfl_down(acc0, off, 64);
        acc1 += __shfl_down(acc1, off, 64);
    }

    __shared__ float red0[4], red1[4];
    __shared__ float lut0[64], lut1[64];   // 51 used each, padded
    if ((t & 63) == 0) { red0[t >> 6] = acc0; red1[t >> 6] = acc1; }
    __syncthreads();

    // ---- LIF + STDP LUTs: row0 on wave 0, row1 on wave 1 (concurrent) ----
    if (t < 51) {
        const float weighted = red0[0] + red0[1] + red0[2] + red0[3];
        const float mem   = m0 * kBeta + weighted;
        const bool  fired = mem > kThresh;
        const float ndf   = fired ? 0.0f : (df0 + 1.0f);
        const float dt    = ndf - (float)t;            // delta_t for ndp == t
        float ch = 0.0f;
        if (dt > 0.0f)      ch =  kA * expf(-dt * kInvTau);
        else if (dt < 0.0f) ch = -kA * expf( dt * kInvTau);
        lut0[t] = ch;
        if (t == 0) {
            out[r0]             = fired ? 1.0f : 0.0f;
            out[OUT_F + r0]     = fired ? (mem - kReset) : mem;
            out[3 * OUT_F + r0] = ndf;
        }
    } else if (t >= 64 && t < 115) {
        const int   u = t - 64;
        const float weighted = red1[0] + red1[1] + red1[2] + red1[3];
        const float mem   = m1 * kBeta + weighted;
        const bool  fired = mem > kThresh;
        const float ndf   = fired ? 0.0f : (df1 + 1.0f);
        const float dt    = ndf - (float)u;
        float ch = 0.0f;
        if (dt > 0.0f)      ch =  kA * expf(-dt * kInvTau);
        else if (dt < 0.0f) ch = -kA * expf( dt * kInvTau);
        lut1[u] = ch;
        if (u == 0) {
            out[r1]             = fired ? 1.0f : 0.0f;
            out[OUT_F + r1]     = fired ? (mem - kReset) : mem;
            out[3 * OUT_F + r1] = ndf;
        }
    }
    __syncthreads();

    // ---- pass 2: both rows' weight updates from registers + LUTs, streaming stores ----
    float* o0 = out + 4 * OUT_F + (size_t)r0 * IN_F;
    float* o1 = out + 4 * OUT_F + (size_t)r1 * IN_F;
#pragma unroll
    for (int k = 0; k < 8; ++k) {
        const int c = k * 1024 + t * 4;
        const unsigned p = packed[k];
        const unsigned j0 = p & 0xffu, j1 = (p >> 8) & 0xffu,
                       j2 = (p >> 16) & 0xffu, j3 = p >> 24;
        v4f a, b;
        a.x = w0[k].x + lut0[j0];
        a.y = w0[k].y + lut0[j1];
        a.z = w0[k].z + lut0[j2];
        a.w = w0[k].w + lut0[j3];
        b.x = w1[k].x + lut1[j0];
        b.y = w1[k].y + lut1[j1];
        b.z = w1[k].z + lut1[j2];
        b.w = w1[k].w + lut1[j3];
        __builtin_nontemporal_store(a, (v4f*)(o0 + c));
        __builtin_nontemporal_store(b, (v4f*)(o1 + c));
    }

    // block 0 also materializes the new_delta_pre output vector (from packed indices)
    if (blockIdx.x == 0) {
        float* ondp = out + 2 * OUT_F;
#pragma unroll
        for (int k = 0; k < 8; ++k) {
            const int c = k * 1024 + t * 4;
            const unsigned p = packed[k];
            v4f r;
            r.x = (float)(p & 0xffu);
            r.y = (float)((p >> 8) & 0xffu);
            r.z = (float)((p >> 16) & 0xffu);
            r.w = (float)(p >> 24);
            *(v4f*)(ondp + c) = r;
        }
    }
}

extern "C" void kernel_launch(void* const* d_in, const int* in_sizes, int n_in,
                              void* d_out, int out_size, void* d_ws, size_t ws_size,
                              hipStream_t stream) {
    const float* in_spikes  = (const float*)d_in[0];
    const float* weights    = (const float*)d_in[1];
    const float* membrane   = (const float*)d_in[2];
    const float* delta_pre  = (const float*)d_in[3];
    const float* delta_fire = (const float*)d_in[4];
    float* out = (float*)d_out;

    stdp_fused2<<<OUT_F / 2, 256, 0, stream>>>(in_spikes, weights, membrane,
                                               delta_pre, delta_fire, out);
}